// Round 7
// baseline (19202.551 us; speedup 1.0000x reference)
//
#include <hip/hip_runtime.h>
#include <math.h>

#define TB 256      // batch
#define TT 512      // timesteps
#define TIN 128     // input size
#define TH 1024     // hidden
#define TOUT 9      // output coords
#define KD 1152     // TIN + TH

typedef _Float16 half8 __attribute__((ext_vector_type(8)));
typedef float f32x4 __attribute__((ext_vector_type(4)));

// ---- workspace layout (BYTE offsets) ----
#define OB_WHF   0ull
#define SB_WHF   (128ull*2*36*64*8*2)   // 9,437,184 B  f16 B-fragments [wcg][nt][kc][l][j]
#define OB_WCB   (OB_WHF + SB_WHF)      // Wcombo fp32 [9][1024]
#define SB_WCB   (9ull*1024*4)
#define OB_BCB   (OB_WCB + SB_WCB)      // bcombo fp32 [9] (pad 16)
#define SB_BCB   64ull
#define OB_B0    (OB_BCB + SB_BCB)      // bias t==0 [4096] fp32
#define SB_B0    (4096ull*4)
#define OB_BC    (OB_B0 + SB_B0)        // bias t>0  [4096] fp32
#define SB_BC    (4096ull*4)
#define OB_H0    (OB_BC + SB_BC)        // h_cell ping [256][1024] f16
#define SB_H     (256ull*1024*2)
#define OB_H1    (OB_H0 + SB_H)         // h_cell pong
#define OB_GC    (OB_H1 + SB_H)         // barrier tree counters (128B-spaced)
#define OB_END   (OB_GC + 8192ull)      // ~10.5 MB total

// fragment address for gate col `col` (0..4095), k (0..1151):
//   q=col>>10 (gate), hcol=col&1023, wcg=hcol>>3, jj=hcol&7, c=(q<<3)|jj,
//   nt=c>>4, n=c&15, kc=k>>5, ls=(k>>3)&3, je=k&7, lane=(ls<<4)|n
__device__ __forceinline__ size_t frag_addr(int col, int k) {
  int q = col >> 10, hcol = col & 1023;
  int wcg = hcol >> 3, jj = hcol & 7;
  int c = (q << 3) | jj;
  int nt = c >> 4, n = c & 15;
  int kc = k >> 5, ls = (k >> 3) & 3, je = k & 7;
  return ((((size_t)wcg * 2 + nt) * 36 + kc) * 64 + ((ls << 4) | n)) * 8 + je;
}

// ---- agent-scope (LLC-direct, sc1) 16B h access as 2x8B relaxed atomics ----
__device__ __forceinline__ half8 ld_h16_agent(const _Float16* p) {
  union { unsigned long long u[2]; half8 h; } c;
  c.u[0] = __hip_atomic_load((const unsigned long long*)p,     __ATOMIC_RELAXED, __HIP_MEMORY_SCOPE_AGENT);
  c.u[1] = __hip_atomic_load((const unsigned long long*)p + 1, __ATOMIC_RELAXED, __HIP_MEMORY_SCOPE_AGENT);
  return c.h;
}
__device__ __forceinline__ void st_h16_agent(_Float16* p, uint4 v) {
  union { uint4 q; unsigned long long u[2]; } c; c.q = v;
  __hip_atomic_store((unsigned long long*)p,     c.u[0], __ATOMIC_RELAXED, __HIP_MEMORY_SCOPE_AGENT);
  __hip_atomic_store((unsigned long long*)p + 1, c.u[1], __ATOMIC_RELAXED, __HIP_MEMORY_SCOPE_AGENT);
}

// ---------------- prep kernels (unchanged, verified rounds 5-6) ----------------

__global__ __launch_bounds__(256) void k_combo(const float* __restrict__ W_h2o,
                                               const float* __restrict__ W_h2h,
                                               const float* __restrict__ b_h2h,
                                               const float* __restrict__ b_h2o,
                                               float* __restrict__ Wcombo,
                                               float* __restrict__ bcombo) {
  int gid = blockIdx.x * 256 + threadIdx.x;
  if (gid < 9 * 1024) {
    int r = gid >> 10, m = gid & 1023;
    float s = 0.f;
    for (int j = 0; j < 1024; ++j) s += W_h2o[r * 1024 + j] * W_h2h[j * 1024 + m];
    Wcombo[gid] = s;
  }
  if (gid < 9) {
    float s = b_h2o[gid];
    for (int j = 0; j < 1024; ++j) s += W_h2o[gid * 1024 + j] * b_h2h[j];
    bcombo[gid] = s;
  }
}

__global__ __launch_bounds__(256) void k_wblk(const float* __restrict__ W_hh,
                                              const float* __restrict__ W_ih,
                                              const float* __restrict__ W_h2o,
                                              const float* __restrict__ W_h2h,
                                              _Float16* __restrict__ Whf) {
  __shared__ float As2[16][68];
  __shared__ float Bs[16][68];
  __shared__ float Wio_s[64][12];
  __shared__ float Bo[9][16];
  const int tid = threadIdx.x;
  const int bm = (blockIdx.x & 15) * 64;   // m tile
  const int bc = (blockIdx.x >> 4) * 64;   // col tile
  const int tx = tid & 15, ty = tid >> 4;
  const int cl = tid >> 2, kq4 = tid & 3;

  for (int i = tid; i < 64 * 9; i += 256) {
    int row = i / 9, r = i % 9;
    Wio_s[row][r] = W_ih[(size_t)(bc + row) * 137 + 128 + r];
  }

  float acc[4][4];
#pragma unroll
  for (int i = 0; i < 4; ++i)
#pragma unroll
    for (int j = 0; j < 4; ++j) acc[i][j] = 0.f;

  for (int k0 = 0; k0 < 1024; k0 += 16) {
    __syncthreads();
    if (tid < 144) { int r = tid >> 4, kk = tid & 15; Bo[r][kk] = W_h2o[(size_t)r * 1024 + k0 + kk]; }
    { int kk = tid >> 4, q = tid & 15;
      float4 v = *(const float4*)(W_h2h + (size_t)(k0 + kk) * 1024 + bm + q * 4);
      *(float4*)&Bs[kk][q * 4] = v; }
    float4 av = *(const float4*)(W_hh + (size_t)(bc + cl) * 1024 + k0 + kq4 * 4);
    __syncthreads();
    {
      float c0 = 0.f, c1 = 0.f, c2 = 0.f, c3 = 0.f;
#pragma unroll
      for (int r = 0; r < 9; ++r) {
        float wio = Wio_s[cl][r];
        c0 += wio * Bo[r][kq4 * 4 + 0];
        c1 += wio * Bo[r][kq4 * 4 + 1];
        c2 += wio * Bo[r][kq4 * 4 + 2];
        c3 += wio * Bo[r][kq4 * 4 + 3];
      }
      As2[kq4 * 4 + 0][cl] = av.x + c0;
      As2[kq4 * 4 + 1][cl] = av.y + c1;
      As2[kq4 * 4 + 2][cl] = av.z + c2;
      As2[kq4 * 4 + 3][cl] = av.w + c3;
    }
    __syncthreads();
#pragma unroll
    for (int kk = 0; kk < 16; ++kk) {
      float4 a = *(const float4*)&As2[kk][ty * 4];
      float4 bv = *(const float4*)&Bs[kk][tx * 4];
      acc[0][0] += a.x * bv.x; acc[0][1] += a.x * bv.y; acc[0][2] += a.x * bv.z; acc[0][3] += a.x * bv.w;
      acc[1][0] += a.y * bv.x; acc[1][1] += a.y * bv.y; acc[1][2] += a.y * bv.z; acc[1][3] += a.y * bv.w;
      acc[2][0] += a.z * bv.x; acc[2][1] += a.z * bv.y; acc[2][2] += a.z * bv.z; acc[2][3] += a.z * bv.w;
      acc[3][0] += a.w * bv.x; acc[3][1] += a.w * bv.y; acc[3][2] += a.w * bv.z; acc[3][3] += a.w * bv.w;
    }
  }
#pragma unroll
  for (int i = 0; i < 4; ++i)
#pragma unroll
    for (int j = 0; j < 4; ++j) {
      int col = bc + ty * 4 + i;          // gate col
      int m = bm + tx * 4 + j;            // h index -> k = 128+m
      Whf[frag_addr(col, 128 + m)] = (_Float16)acc[i][j];
    }
}

__global__ __launch_bounds__(256) void k_bias(const float* __restrict__ b_ih,
                                              const float* __restrict__ b_hh,
                                              const float* __restrict__ W_hh,
                                              const float* __restrict__ W_ih,
                                              const float* __restrict__ b_h2h,
                                              const float* __restrict__ bcombo,
                                              float* __restrict__ b0,
                                              float* __restrict__ bconst) {
  int col = blockIdx.x * 256 + threadIdx.x;
  float base = b_ih[col] + b_hh[col];
  b0[col] = base;
  float s = 0.f;
  for (int j = 0; j < 1024; ++j) s += W_hh[(size_t)col * 1024 + j] * b_h2h[j];
#pragma unroll
  for (int r = 0; r < 9; ++r) s += W_ih[(size_t)col * 137 + 128 + r] * bcombo[r];
  bconst[col] = base + s;
}

__global__ __launch_bounds__(256) void k_fillx(const float* __restrict__ W_ih,
                                               _Float16* __restrict__ Whf) {
  int gid = blockIdx.x * 256 + threadIdx.x;   // 4096*128
  int col = gid >> 7, k = gid & 127;
  Whf[frag_addr(col, k)] = (_Float16)W_ih[(size_t)col * 137 + k];
}

__global__ void k_len(const int* __restrict__ len, float* __restrict__ dout) {
  int i = threadIdx.x;
  if (i < TB) dout[(size_t)TB * TT * TOUT + i] = (float)len[i];
}

// ---------------- persistent main kernel ----------------
// 256 blocks (1/CU, forced by 117KB LDS) x 1024 thr. Block = (batch-half, wcg).
// W fragments LDS-resident across ALL 512 steps. Waves: mt=wv&7 (M-tile of 16
// batches), kh=wv>>3 (K-half of 576); each wave computes BOTH N-tiles from one
// A-fragment (no redundant h reads). h exchange: agent-scope (sc1, LLC-direct)
// relaxed atomics — no fences anywhere. Grid sync: 2-level tree barrier
// (16 groups x 16), tid0-only, relaxed atomics, bounded spin + global abort.

__device__ __forceinline__ float sigm(float v) { return 1.f / (1.f + __expf(-v)); }
__device__ __forceinline__ float tanh_f(float v) {
  float e2 = __expf(2.f * v);
  return (e2 - 1.f) / (e2 + 1.f);
}

__global__ __launch_bounds__(1024, 1) void k_main(const float* __restrict__ x,
                                                  const _Float16* __restrict__ Whf,
                                                  const float* __restrict__ Wc,
                                                  const float* __restrict__ b0,
                                                  const float* __restrict__ bcf,
                                                  const float* __restrict__ bcombo,
                                                  _Float16* __restrict__ hA,
                                                  _Float16* __restrict__ hB,
                                                  unsigned* __restrict__ gs,
                                                  float* __restrict__ dout) {
  __shared__ _Float16 Wl[2 * 36 * 64 * 8];   // 73,728 B
  __shared__ float gbuf[2][128][36];         // 36,864 B (K-half partials)
  __shared__ _Float16 htmp[128][8];          //  2,048 B
  __shared__ float obuf[128][8];             //  4,096 B
  __shared__ float bias_s[2][32];
  __shared__ float sBco;
  __shared__ int sAbort;

  const int bx = blockIdx.x;
  const int wcg = bx & 127;          // col-group: h-cols 8*wcg..+7
  const int B0 = (bx >> 7) * 128;    // batch base
  const int grp = bx >> 4;           // barrier group (16 blocks each)
  const int tid = threadIdx.x;
  const int lane = tid & 63;
  const int wv = tid >> 6;
  const int mt = wv & 7, kh = wv >> 3;

  unsigned* gcnt_grp = gs + grp * 32;        // arrival counter (own 128B line)
  unsigned* gcnt_root = gs + 16 * 32;        // root counter
  unsigned* grel = gs + (17 + grp) * 32;     // group release word
  unsigned* gabort = gs + 33 * 32;           // global abort flag

  {  // stage W fragments once (reused 512 steps)
    const uint4* src = (const uint4*)(Whf + (size_t)wcg * (2 * 36 * 64 * 8));
    uint4* dst = (uint4*)Wl;
    for (int i = tid; i < 2 * 36 * 64 * 8 / 8; i += 1024) dst[i] = src[i];
  }
  if (tid == 0) { sAbort = 0; sBco = (wcg < TOUT) ? bcombo[wcg] : 0.f; }
  if (tid < 32) {
    int g = (tid >> 3) * 1024 + wcg * 8 + (tid & 7);   // c=(q<<3)|jj -> gate col
    bias_s[0][tid] = b0[g];
    bias_s[1][tid] = bcf[g];
  }
  float cs = 0.f;   // cell state of (batch B0+(tid>>3), h-col 8*wcg+(tid&7))
  __syncthreads();

  const _Float16* ha = hA;   // h_cell(t-1), zeroed by memset
  _Float16* hn = hB;

  const int bA = B0 + mt * 16 + (lane & 15);   // A-fragment batch row
  const int ko = (lane >> 4) * 8;              // A-fragment k offset within 32-chunk
  const _Float16* wl0 = Wl + (size_t)lane * 8;
  const int fbo = tid & 127, fjo = tid >> 7;   // out-column split
  unsigned myLead = 0;

  for (int t = 0; t < TT; ++t) {
    // ---- MFMA phase: wave (mt,kh) does K-half for BOTH N-tiles ----
    f32x4 acc0 = {0.f, 0.f, 0.f, 0.f};
    f32x4 acc1 = {0.f, 0.f, 0.f, 0.f};
    const float* xrow = x + ((size_t)bA * TT + t) * TIN;
    const _Float16* hrow = ha + (size_t)bA * TH;
#pragma unroll
    for (int lc = 0; lc < 18; ++lc) {
      const int kcg = kh * 18 + lc;
      half8 af;
      if (kh == 0 && lc < 4) {                 // x part (k<128), fp32->f16
        float4 xa = *(const float4*)(xrow + lc * 32 + ko);
        float4 xb = *(const float4*)(xrow + lc * 32 + ko + 4);
        af[0] = (_Float16)xa.x; af[1] = (_Float16)xa.y; af[2] = (_Float16)xa.z; af[3] = (_Float16)xa.w;
        af[4] = (_Float16)xb.x; af[5] = (_Float16)xb.y; af[6] = (_Float16)xb.z; af[7] = (_Float16)xb.w;
      } else {                                 // h part: LLC-direct load
        af = ld_h16_agent(hrow + (kcg * 32 - 128 + ko));
      }
      half8 bf0 = *(const half8*)(wl0 + (size_t)kcg * 512);
      half8 bf1 = *(const half8*)(wl0 + (size_t)(36 + kcg) * 512);
      acc0 = __builtin_amdgcn_mfma_f32_16x16x32_f16(af, bf0, acc0, 0, 0, 0);
      acc1 = __builtin_amdgcn_mfma_f32_16x16x32_f16(af, bf1, acc1, 0, 0, 0);
    }
    {  // D layout: col = lane&15, row = (lane>>4)*4 + r
      int rb = mt * 16 + (lane >> 4) * 4;
      int cc = lane & 15;
#pragma unroll
      for (int r = 0; r < 4; ++r) {
        gbuf[kh][rb + r][cc] = acc0[r];
        gbuf[kh][rb + r][16 + cc] = acc1[r];
      }
    }
    __syncthreads();

    // ---- LSTM finish: thread owns (fb=tid>>3, fj=tid&7); cs in registers ----
    {
      const int fb = tid >> 3, fj = tid & 7;
      const float* bs = bias_s[(t > 0) ? 1 : 0];
      float vi = gbuf[0][fb][fj]      + gbuf[1][fb][fj]      + bs[fj];
      float vf = gbuf[0][fb][8 + fj]  + gbuf[1][fb][8 + fj]  + bs[8 + fj];
      float vg = gbuf[0][fb][16 + fj] + gbuf[1][fb][16 + fj] + bs[16 + fj];
      float vo = gbuf[0][fb][24 + fj] + gbuf[1][fb][24 + fj] + bs[24 + fj];
      float ig = sigm(vi), fg = sigm(vf), gg = tanh_f(vg), og = sigm(vo);
      float cn = fg * cs + ig * gg;
      cs = cn;
      htmp[fb][fj] = (_Float16)(og * tanh_f(cn));
    }
    __syncthreads();

    // ---- h store: LLC-direct (sc1); drained by the next __syncthreads ----
    if (tid < 128) {
      uint4 hv = *(const uint4*)&htmp[tid][0];
      st_h16_agent(hn + (size_t)(B0 + tid) * TH + 8 * wcg, hv);
    }
    __syncthreads();   // hipcc emits s_waitcnt vmcnt(0) per thread -> stores at LLC

    // ---- barrier arrival (relaxed: data already drained to LLC) ----
    if (tid == 0) {
      unsigned old = __hip_atomic_fetch_add(gcnt_grp, 1u, __ATOMIC_RELAXED, __HIP_MEMORY_SCOPE_AGENT);
      myLead = (old == (unsigned)(t + 1) * 16u - 1u);
    }

    // ---- out(t-1) GEMV (18 of 256 blocks) — overlaps the barrier spin ----
    if (wcg < TOUT && t > 0) {
      const _Float16* hro = ha + (size_t)(B0 + fbo) * TH + fjo * 128;
      const float* wcp = Wc + wcg * 1024 + fjo * 128;
      float s = 0.f;
#pragma unroll 4
      for (int u = 0; u < 16; ++u) {
        half8 hv = ld_h16_agent(hro + u * 8);
#pragma unroll
        for (int i2 = 0; i2 < 8; ++i2) s += (float)hv[i2] * wcp[u * 8 + i2];
      }
      obuf[fbo][fjo] = s;
    }
    __syncthreads();
    if (wcg < TOUT && t > 0 && tid < 128) {
      float s = obuf[tid][0] + obuf[tid][1] + obuf[tid][2] + obuf[tid][3]
              + obuf[tid][4] + obuf[tid][5] + obuf[tid][6] + obuf[tid][7] + sBco;
      dout[((size_t)(B0 + tid) * TT + (t - 1)) * TOUT + wcg] = s;
    }

    // ---- barrier spin (tree; bounded; global abort) ----
    if (tid == 0) {
      bool ab = false;
      unsigned guard = 0;
      if (myLead) {
        __hip_atomic_fetch_add(gcnt_root, 1u, __ATOMIC_RELAXED, __HIP_MEMORY_SCOPE_AGENT);
        while (__hip_atomic_load(gcnt_root, __ATOMIC_RELAXED, __HIP_MEMORY_SCOPE_AGENT) < (unsigned)(t + 1) * 16u) {
          __builtin_amdgcn_s_sleep(2);
          if (((++guard) & 255u) == 0u &&
              __hip_atomic_load(gabort, __ATOMIC_RELAXED, __HIP_MEMORY_SCOPE_AGENT) != 0u) { ab = true; break; }
          if (guard > 200000u) {
            __hip_atomic_store(gabort, 1u, __ATOMIC_RELAXED, __HIP_MEMORY_SCOPE_AGENT);
            ab = true; break;
          }
        }
        if (!ab) __hip_atomic_store(grel, (unsigned)(t + 1), __ATOMIC_RELAXED, __HIP_MEMORY_SCOPE_AGENT);
      } else {
        while (__hip_atomic_load(grel, __ATOMIC_RELAXED, __HIP_MEMORY_SCOPE_AGENT) < (unsigned)(t + 1)) {
          __builtin_amdgcn_s_sleep(2);
          if (((++guard) & 255u) == 0u &&
              __hip_atomic_load(gabort, __ATOMIC_RELAXED, __HIP_MEMORY_SCOPE_AGENT) != 0u) { ab = true; break; }
          if (guard > 200000u) {
            __hip_atomic_store(gabort, 1u, __ATOMIC_RELAXED, __HIP_MEMORY_SCOPE_AGENT);
            ab = true; break;
          }
        }
      }
      if (ab) sAbort = 1;
    }
    __syncthreads();
    if (sAbort) return;   // wrong answer beats a wedged GPU

    const _Float16* tp = ha; ha = hn; hn = (_Float16*)tp;
  }

  // ---- epilogue: out(TT-1) from final h (visible after last barrier) ----
  if (wcg < TOUT) {
    const _Float16* hro = ha + (size_t)(B0 + fbo) * TH + fjo * 128;
    const float* wcp = Wc + wcg * 1024 + fjo * 128;
    float s = 0.f;
#pragma unroll 4
    for (int u = 0; u < 16; ++u) {
      half8 hv = ld_h16_agent(hro + u * 8);
#pragma unroll
      for (int i2 = 0; i2 < 8; ++i2) s += (float)hv[i2] * wcp[u * 8 + i2];
    }
    obuf[fbo][fjo] = s;
    __syncthreads();
    if (tid < 128) {
      float s2 = obuf[tid][0] + obuf[tid][1] + obuf[tid][2] + obuf[tid][3]
               + obuf[tid][4] + obuf[tid][5] + obuf[tid][6] + obuf[tid][7] + sBco;
      dout[((size_t)(B0 + tid) * TT + (TT - 1)) * TOUT + wcg] = s2;
    }
  }
}

// ---------------- launch ----------------

extern "C" void kernel_launch(void* const* d_in, const int* in_sizes, int n_in,
                              void* d_out, int out_size, void* d_ws, size_t ws_size,
                              hipStream_t stream) {
  if (ws_size < OB_END) return;   // clean fail, no OOB

  const float* x     = (const float*)d_in[0];
  const float* W_ih  = (const float*)d_in[1];
  const float* b_ih  = (const float*)d_in[2];
  const float* W_hh  = (const float*)d_in[3];
  const float* b_hh  = (const float*)d_in[4];
  const float* W_h2h = (const float*)d_in[5];
  const float* b_h2h = (const float*)d_in[6];
  const float* W_h2o = (const float*)d_in[7];
  const float* b_h2o = (const float*)d_in[8];
  const int*   lens  = (const int*)d_in[9];

  char* ws = (char*)d_ws;
  float* dout    = (float*)d_out;
  _Float16* Whf  = (_Float16*)(ws + OB_WHF);
  float* Wcombo  = (float*)(ws + OB_WCB);
  float* bcombo  = (float*)(ws + OB_BCB);
  float* b0      = (float*)(ws + OB_B0);
  float* bconst  = (float*)(ws + OB_BC);
  _Float16* h0   = (_Float16*)(ws + OB_H0);
  _Float16* h1   = (_Float16*)(ws + OB_H1);
  unsigned* gs   = (unsigned*)(ws + OB_GC);

  // zero h ping-pong + barrier counters every call (graph-replay safe)
  hipMemsetAsync((void*)(ws + OB_H0), 0, OB_END - OB_H0, stream);

  k_combo<<<36, 256, 0, stream>>>(W_h2o, W_h2h, b_h2h, b_h2o, Wcombo, bcombo);
  k_wblk<<<1024, 256, 0, stream>>>(W_hh, W_ih, W_h2o, W_h2h, Whf);
  k_bias<<<16, 256, 0, stream>>>(b_ih, b_hh, W_hh, W_ih, b_h2h, bcombo, b0, bconst);
  k_fillx<<<2048, 256, 0, stream>>>(W_ih, Whf);
  k_len<<<1, 256, 0, stream>>>(lens, dout);

  k_main<<<256, 1024, 0, stream>>>(x, Whf, Wcombo, b0, bconst, bcombo, h0, h1, gs, dout);
}

// Round 8
// 12658.329 us; speedup vs baseline: 1.5170x; 1.5170x over previous
//
#include <hip/hip_runtime.h>
#include <math.h>

#define TB 256      // batch
#define TT 512      // timesteps
#define TIN 128     // input size
#define TH 1024     // hidden
#define TOUT 9      // output coords
#define KD 1152     // TIN + TH

typedef _Float16 half8 __attribute__((ext_vector_type(8)));
typedef float f32x4 __attribute__((ext_vector_type(4)));

// ---- workspace layout (BYTE offsets) ----
#define OB_WHF   0ull
#define SB_WHF   (128ull*2*36*64*8*2)   // 9,437,184 B  f16 B-fragments [wcg][nt][kc][l][j]
#define OB_WCB   (OB_WHF + SB_WHF)      // Wcombo fp32 [9][1024]
#define SB_WCB   (9ull*1024*4)
#define OB_BCB   (OB_WCB + SB_WCB)      // bcombo fp32 [9] (pad 16)
#define SB_BCB   64ull
#define OB_B0    (OB_BCB + SB_BCB)      // bias t==0 [4096] fp32
#define SB_B0    (4096ull*4)
#define OB_BC    (OB_B0 + SB_B0)        // bias t>0  [4096] fp32
#define SB_BC    (4096ull*4)
#define OB_H0    (OB_BC + SB_BC)        // h_cell ping [256][1024] f16
#define SB_H     (256ull*1024*2)
#define OB_H1    (OB_H0 + SB_H)         // h_cell pong
#define OB_GC    (OB_H1 + SB_H)         // barrier tree counters (128B-spaced)
#define OB_END   (OB_GC + 8192ull)      // ~10.5 MB total

// fragment address for gate col `col` (0..4095), k (0..1151):
//   q=col>>10 (gate), hcol=col&1023, wcg=hcol>>3, jj=hcol&7, c=(q<<3)|jj,
//   nt=c>>4, n=c&15, kc=k>>5, ls=(k>>3)&3, je=k&7, lane=(ls<<4)|n
__device__ __forceinline__ size_t frag_addr(int col, int k) {
  int q = col >> 10, hcol = col & 1023;
  int wcg = hcol >> 3, jj = hcol & 7;
  int c = (q << 3) | jj;
  int nt = c >> 4, n = c & 15;
  int kc = k >> 5, ls = (k >> 3) & 3, je = k & 7;
  return ((((size_t)wcg * 2 + nt) * 36 + kc) * 64 + ((ls << 4) | n)) * 8 + je;
}

// ---- agent-scope (LLC write-through) 16B h store as 2x8B relaxed atomics ----
__device__ __forceinline__ void st_h16_agent(_Float16* p, uint4 v) {
  union { uint4 q; unsigned long long u[2]; } c; c.q = v;
  __hip_atomic_store((unsigned long long*)p,     c.u[0], __ATOMIC_RELAXED, __HIP_MEMORY_SCOPE_AGENT);
  __hip_atomic_store((unsigned long long*)p + 1, c.u[1], __ATOMIC_RELAXED, __HIP_MEMORY_SCOPE_AGENT);
}

// ---------------- prep kernels (unchanged, verified rounds 5-7) ----------------

__global__ __launch_bounds__(256) void k_combo(const float* __restrict__ W_h2o,
                                               const float* __restrict__ W_h2h,
                                               const float* __restrict__ b_h2h,
                                               const float* __restrict__ b_h2o,
                                               float* __restrict__ Wcombo,
                                               float* __restrict__ bcombo) {
  int gid = blockIdx.x * 256 + threadIdx.x;
  if (gid < 9 * 1024) {
    int r = gid >> 10, m = gid & 1023;
    float s = 0.f;
    for (int j = 0; j < 1024; ++j) s += W_h2o[r * 1024 + j] * W_h2h[j * 1024 + m];
    Wcombo[gid] = s;
  }
  if (gid < 9) {
    float s = b_h2o[gid];
    for (int j = 0; j < 1024; ++j) s += W_h2o[gid * 1024 + j] * b_h2h[j];
    bcombo[gid] = s;
  }
}

__global__ __launch_bounds__(256) void k_wblk(const float* __restrict__ W_hh,
                                              const float* __restrict__ W_ih,
                                              const float* __restrict__ W_h2o,
                                              const float* __restrict__ W_h2h,
                                              _Float16* __restrict__ Whf) {
  __shared__ float As2[16][68];
  __shared__ float Bs[16][68];
  __shared__ float Wio_s[64][12];
  __shared__ float Bo[9][16];
  const int tid = threadIdx.x;
  const int bm = (blockIdx.x & 15) * 64;   // m tile
  const int bc = (blockIdx.x >> 4) * 64;   // col tile
  const int tx = tid & 15, ty = tid >> 4;
  const int cl = tid >> 2, kq4 = tid & 3;

  for (int i = tid; i < 64 * 9; i += 256) {
    int row = i / 9, r = i % 9;
    Wio_s[row][r] = W_ih[(size_t)(bc + row) * 137 + 128 + r];
  }

  float acc[4][4];
#pragma unroll
  for (int i = 0; i < 4; ++i)
#pragma unroll
    for (int j = 0; j < 4; ++j) acc[i][j] = 0.f;

  for (int k0 = 0; k0 < 1024; k0 += 16) {
    __syncthreads();
    if (tid < 144) { int r = tid >> 4, kk = tid & 15; Bo[r][kk] = W_h2o[(size_t)r * 1024 + k0 + kk]; }
    { int kk = tid >> 4, q = tid & 15;
      float4 v = *(const float4*)(W_h2h + (size_t)(k0 + kk) * 1024 + bm + q * 4);
      *(float4*)&Bs[kk][q * 4] = v; }
    float4 av = *(const float4*)(W_hh + (size_t)(bc + cl) * 1024 + k0 + kq4 * 4);
    __syncthreads();
    {
      float c0 = 0.f, c1 = 0.f, c2 = 0.f, c3 = 0.f;
#pragma unroll
      for (int r = 0; r < 9; ++r) {
        float wio = Wio_s[cl][r];
        c0 += wio * Bo[r][kq4 * 4 + 0];
        c1 += wio * Bo[r][kq4 * 4 + 1];
        c2 += wio * Bo[r][kq4 * 4 + 2];
        c3 += wio * Bo[r][kq4 * 4 + 3];
      }
      As2[kq4 * 4 + 0][cl] = av.x + c0;
      As2[kq4 * 4 + 1][cl] = av.y + c1;
      As2[kq4 * 4 + 2][cl] = av.z + c2;
      As2[kq4 * 4 + 3][cl] = av.w + c3;
    }
    __syncthreads();
#pragma unroll
    for (int kk = 0; kk < 16; ++kk) {
      float4 a = *(const float4*)&As2[kk][ty * 4];
      float4 bv = *(const float4*)&Bs[kk][tx * 4];
      acc[0][0] += a.x * bv.x; acc[0][1] += a.x * bv.y; acc[0][2] += a.x * bv.z; acc[0][3] += a.x * bv.w;
      acc[1][0] += a.y * bv.x; acc[1][1] += a.y * bv.y; acc[1][2] += a.y * bv.z; acc[1][3] += a.y * bv.w;
      acc[2][0] += a.z * bv.x; acc[2][1] += a.z * bv.y; acc[2][2] += a.z * bv.z; acc[2][3] += a.z * bv.w;
      acc[3][0] += a.w * bv.x; acc[3][1] += a.w * bv.y; acc[3][2] += a.w * bv.z; acc[3][3] += a.w * bv.w;
    }
  }
#pragma unroll
  for (int i = 0; i < 4; ++i)
#pragma unroll
    for (int j = 0; j < 4; ++j) {
      int col = bc + ty * 4 + i;          // gate col
      int m = bm + tx * 4 + j;            // h index -> k = 128+m
      Whf[frag_addr(col, 128 + m)] = (_Float16)acc[i][j];
    }
}

__global__ __launch_bounds__(256) void k_bias(const float* __restrict__ b_ih,
                                              const float* __restrict__ b_hh,
                                              const float* __restrict__ W_hh,
                                              const float* __restrict__ W_ih,
                                              const float* __restrict__ b_h2h,
                                              const float* __restrict__ bcombo,
                                              float* __restrict__ b0,
                                              float* __restrict__ bconst) {
  int col = blockIdx.x * 256 + threadIdx.x;
  float base = b_ih[col] + b_hh[col];
  b0[col] = base;
  float s = 0.f;
  for (int j = 0; j < 1024; ++j) s += W_hh[(size_t)col * 1024 + j] * b_h2h[j];
#pragma unroll
  for (int r = 0; r < 9; ++r) s += W_ih[(size_t)col * 137 + 128 + r] * bcombo[r];
  bconst[col] = base + s;
}

__global__ __launch_bounds__(256) void k_fillx(const float* __restrict__ W_ih,
                                               _Float16* __restrict__ Whf) {
  int gid = blockIdx.x * 256 + threadIdx.x;   // 4096*128
  int col = gid >> 7, k = gid & 127;
  Whf[frag_addr(col, k)] = (_Float16)W_ih[(size_t)col * 137 + k];
}

__global__ void k_len(const int* __restrict__ len, float* __restrict__ dout) {
  int i = threadIdx.x;
  if (i < TB) dout[(size_t)TB * TT * TOUT + i] = (float)len[i];
}

// ---------------- persistent main kernel ----------------
// 256 blocks (1/CU, forced by 117KB LDS) x 1024 thr. Block = (batch-half, wcg).
// W fragments LDS-resident across ALL 512 steps. Waves: mt=wv&7, kh=wv>>3.
// h exchange: WRITE-THROUGH agent atomics (512 KB/step) + CACHED reads
// (64 MB/step broadcast served by L2) + one invalidate-only acquire
// (__hip_atomic_load ACQUIRE -> buffer_inv, no wbl2) per block per step.
// Grid sync: 2-level tree barrier, tid0-only, relaxed atomics, bounded spin.

__device__ __forceinline__ float sigm(float v) { return 1.f / (1.f + __expf(-v)); }
__device__ __forceinline__ float tanh_f(float v) {
  float e2 = __expf(2.f * v);
  return (e2 - 1.f) / (e2 + 1.f);
}

__global__ __launch_bounds__(1024, 1) void k_main(const float* __restrict__ x,
                                                  const _Float16* __restrict__ Whf,
                                                  const float* __restrict__ Wc,
                                                  const float* __restrict__ b0,
                                                  const float* __restrict__ bcf,
                                                  const float* __restrict__ bcombo,
                                                  _Float16* __restrict__ hA,
                                                  _Float16* __restrict__ hB,
                                                  unsigned* __restrict__ gs,
                                                  float* __restrict__ dout) {
  __shared__ _Float16 Wl[2 * 36 * 64 * 8];   // 73,728 B
  __shared__ float gbuf[2][128][36];         // 36,864 B (K-half partials)
  __shared__ _Float16 htmp[128][8];          //  2,048 B
  __shared__ float obuf[128][8];             //  4,096 B
  __shared__ float bias_s[2][32];
  __shared__ float sBco;
  __shared__ int sAbort;

  const int bx = blockIdx.x;
  const int wcg = bx & 127;          // col-group: h-cols 8*wcg..+7
  const int B0 = (bx >> 7) * 128;    // batch base
  const int grp = bx >> 4;           // barrier group (16 blocks each)
  const int tid = threadIdx.x;
  const int lane = tid & 63;
  const int wv = tid >> 6;
  const int mt = wv & 7, kh = wv >> 3;

  unsigned* gcnt_grp = gs + grp * 32;        // arrival counter (own 128B line)
  unsigned* gcnt_root = gs + 16 * 32;        // root counter
  unsigned* grel = gs + (17 + grp) * 32;     // group release word
  unsigned* gabort = gs + 33 * 32;           // global abort flag

  {  // stage W fragments once (reused 512 steps)
    const uint4* src = (const uint4*)(Whf + (size_t)wcg * (2 * 36 * 64 * 8));
    uint4* dst = (uint4*)Wl;
    for (int i = tid; i < 2 * 36 * 64 * 8 / 8; i += 1024) dst[i] = src[i];
  }
  if (tid == 0) { sAbort = 0; sBco = (wcg < TOUT) ? bcombo[wcg] : 0.f; }
  if (tid < 32) {
    int g = (tid >> 3) * 1024 + wcg * 8 + (tid & 7);   // c=(q<<3)|jj -> gate col
    bias_s[0][tid] = b0[g];
    bias_s[1][tid] = bcf[g];
  }
  float cs = 0.f;   // cell state of (batch B0+(tid>>3), h-col 8*wcg+(tid&7))
  __syncthreads();

  const _Float16* ha = hA;   // h_cell(t-1), zeroed by memset
  _Float16* hn = hB;

  const int bA = B0 + mt * 16 + (lane & 15);   // A-fragment batch row
  const int ko = (lane >> 4) * 8;              // A-fragment k offset within 32-chunk
  const _Float16* wl0 = Wl + (size_t)lane * 8;
  const int fbo = tid & 127, fjo = tid >> 7;   // out-column split
  unsigned myLead = 0;

  for (int t = 0; t < TT; ++t) {
    // ---- MFMA phase: wave (mt,kh) does K-half for BOTH N-tiles ----
    f32x4 acc0 = {0.f, 0.f, 0.f, 0.f};
    f32x4 acc1 = {0.f, 0.f, 0.f, 0.f};
    const float* xrow = x + ((size_t)bA * TT + t) * TIN;
    const _Float16* hrow = ha + (size_t)bA * TH;
#pragma unroll
    for (int lc = 0; lc < 18; ++lc) {
      const int kcg = kh * 18 + lc;
      half8 af;
      if (kh == 0 && lc < 4) {                 // x part (k<128), fp32->f16
        float4 xa = *(const float4*)(xrow + lc * 32 + ko);
        float4 xb = *(const float4*)(xrow + lc * 32 + ko + 4);
        af[0] = (_Float16)xa.x; af[1] = (_Float16)xa.y; af[2] = (_Float16)xa.z; af[3] = (_Float16)xa.w;
        af[4] = (_Float16)xb.x; af[5] = (_Float16)xb.y; af[6] = (_Float16)xb.z; af[7] = (_Float16)xb.w;
      } else {                                 // h part: CACHED load (L1/L2)
        af = *(const half8*)(hrow + (kcg * 32 - 128 + ko));
      }
      half8 bf0 = *(const half8*)(wl0 + (size_t)kcg * 512);
      half8 bf1 = *(const half8*)(wl0 + (size_t)(36 + kcg) * 512);
      acc0 = __builtin_amdgcn_mfma_f32_16x16x32_f16(af, bf0, acc0, 0, 0, 0);
      acc1 = __builtin_amdgcn_mfma_f32_16x16x32_f16(af, bf1, acc1, 0, 0, 0);
    }
    {  // D layout: col = lane&15, row = (lane>>4)*4 + r
      int rb = mt * 16 + (lane >> 4) * 4;
      int cc = lane & 15;
#pragma unroll
      for (int r = 0; r < 4; ++r) {
        gbuf[kh][rb + r][cc] = acc0[r];
        gbuf[kh][rb + r][16 + cc] = acc1[r];
      }
    }
    __syncthreads();

    // ---- LSTM finish: thread owns (fb=tid>>3, fj=tid&7); cs in registers ----
    {
      const int fb = tid >> 3, fj = tid & 7;
      const float* bs = bias_s[(t > 0) ? 1 : 0];
      float vi = gbuf[0][fb][fj]      + gbuf[1][fb][fj]      + bs[fj];
      float vf = gbuf[0][fb][8 + fj]  + gbuf[1][fb][8 + fj]  + bs[8 + fj];
      float vg = gbuf[0][fb][16 + fj] + gbuf[1][fb][16 + fj] + bs[16 + fj];
      float vo = gbuf[0][fb][24 + fj] + gbuf[1][fb][24 + fj] + bs[24 + fj];
      float ig = sigm(vi), fg = sigm(vf), gg = tanh_f(vg), og = sigm(vo);
      float cn = fg * cs + ig * gg;
      cs = cn;
      htmp[fb][fj] = (_Float16)(og * tanh_f(cn));
    }
    __syncthreads();

    // ---- h store: write-through to LLC (agent atomics) ----
    if (tid < 128) {
      uint4 hv = *(const uint4*)&htmp[tid][0];
      st_h16_agent(hn + (size_t)(B0 + tid) * TH + 8 * wcg, hv);
    }
    __threadfence_block();   // drain own vmcnt: stores visible at LLC
    __syncthreads();         // whole block drained

    // ---- barrier arrival (relaxed: data already at LLC) ----
    if (tid == 0) {
      unsigned old = __hip_atomic_fetch_add(gcnt_grp, 1u, __ATOMIC_RELAXED, __HIP_MEMORY_SCOPE_AGENT);
      myLead = (old == (unsigned)(t + 1) * 16u - 1u);
    }

    // ---- out(t-1) GEMV (18 of 256 blocks) — overlaps barrier propagation ----
    if (wcg < TOUT && t > 0) {
      const _Float16* hro = ha + (size_t)(B0 + fbo) * TH + fjo * 128;
      const float* wcp = Wc + wcg * 1024 + fjo * 128;
      float s = 0.f;
#pragma unroll 4
      for (int u = 0; u < 16; ++u) {
        half8 hv = *(const half8*)(hro + u * 8);
#pragma unroll
        for (int i2 = 0; i2 < 8; ++i2) s += (float)hv[i2] * wcp[u * 8 + i2];
      }
      obuf[fbo][fjo] = s;
    }
    __syncthreads();
    if (wcg < TOUT && t > 0 && tid < 128) {
      float s = obuf[tid][0] + obuf[tid][1] + obuf[tid][2] + obuf[tid][3]
              + obuf[tid][4] + obuf[tid][5] + obuf[tid][6] + obuf[tid][7] + sBco;
      dout[((size_t)(B0 + tid) * TT + (t - 1)) * TOUT + wcg] = s;
    }

    // ---- barrier spin (tree; bounded; abort) + invalidate-only acquire ----
    if (tid == 0) {
      bool ab = false;
      unsigned guard = 0;
      if (myLead) {
        __hip_atomic_fetch_add(gcnt_root, 1u, __ATOMIC_RELAXED, __HIP_MEMORY_SCOPE_AGENT);
        while (__hip_atomic_load(gcnt_root, __ATOMIC_RELAXED, __HIP_MEMORY_SCOPE_AGENT) < (unsigned)(t + 1) * 16u) {
          __builtin_amdgcn_s_sleep(2);
          if (((++guard) & 255u) == 0u &&
              __hip_atomic_load(gabort, __ATOMIC_RELAXED, __HIP_MEMORY_SCOPE_AGENT) != 0u) { ab = true; break; }
          if (guard > 200000u) {
            __hip_atomic_store(gabort, 1u, __ATOMIC_RELAXED, __HIP_MEMORY_SCOPE_AGENT);
            ab = true; break;
          }
        }
        if (!ab) __hip_atomic_store(grel, (unsigned)(t + 1), __ATOMIC_RELAXED, __HIP_MEMORY_SCOPE_AGENT);
      } else {
        while (__hip_atomic_load(grel, __ATOMIC_RELAXED, __HIP_MEMORY_SCOPE_AGENT) < (unsigned)(t + 1)) {
          __builtin_amdgcn_s_sleep(2);
          if (((++guard) & 255u) == 0u &&
              __hip_atomic_load(gabort, __ATOMIC_RELAXED, __HIP_MEMORY_SCOPE_AGENT) != 0u) { ab = true; break; }
          if (guard > 200000u) {
            __hip_atomic_store(gabort, 1u, __ATOMIC_RELAXED, __HIP_MEMORY_SCOPE_AGENT);
            ab = true; break;
          }
        }
      }
      if (ab) {
        sAbort = 1;
      } else {
        // ACQUIRE load: emits buffer_inv (invalidate stale L1/L2), no wbl2.
        (void)__hip_atomic_load(grel, __ATOMIC_ACQUIRE, __HIP_MEMORY_SCOPE_AGENT);
      }
    }
    __syncthreads();
    if (sAbort) return;   // wrong answer beats a wedged GPU

    const _Float16* tp = ha; ha = hn; hn = (_Float16*)tp;
  }

  // ---- epilogue: out(TT-1) from final h (acquired at last barrier) ----
  if (wcg < TOUT) {
    const _Float16* hro = ha + (size_t)(B0 + fbo) * TH + fjo * 128;
    const float* wcp = Wc + wcg * 1024 + fjo * 128;
    float s = 0.f;
#pragma unroll 4
    for (int u = 0; u < 16; ++u) {
      half8 hv = *(const half8*)(hro + u * 8);
#pragma unroll
      for (int i2 = 0; i2 < 8; ++i2) s += (float)hv[i2] * wcp[u * 8 + i2];
    }
    obuf[fbo][fjo] = s;
    __syncthreads();
    if (tid < 128) {
      float s2 = obuf[tid][0] + obuf[tid][1] + obuf[tid][2] + obuf[tid][3]
               + obuf[tid][4] + obuf[tid][5] + obuf[tid][6] + obuf[tid][7] + sBco;
      dout[((size_t)(B0 + tid) * TT + (TT - 1)) * TOUT + wcg] = s2;
    }
  }
}

// ---------------- launch ----------------

extern "C" void kernel_launch(void* const* d_in, const int* in_sizes, int n_in,
                              void* d_out, int out_size, void* d_ws, size_t ws_size,
                              hipStream_t stream) {
  if (ws_size < OB_END) return;   // clean fail, no OOB

  const float* x     = (const float*)d_in[0];
  const float* W_ih  = (const float*)d_in[1];
  const float* b_ih  = (const float*)d_in[2];
  const float* W_hh  = (const float*)d_in[3];
  const float* b_hh  = (const float*)d_in[4];
  const float* W_h2h = (const float*)d_in[5];
  const float* b_h2h = (const float*)d_in[6];
  const float* W_h2o = (const float*)d_in[7];
  const float* b_h2o = (const float*)d_in[8];
  const int*   lens  = (const int*)d_in[9];

  char* ws = (char*)d_ws;
  float* dout    = (float*)d_out;
  _Float16* Whf  = (_Float16*)(ws + OB_WHF);
  float* Wcombo  = (float*)(ws + OB_WCB);
  float* bcombo  = (float*)(ws + OB_BCB);
  float* b0      = (float*)(ws + OB_B0);
  float* bconst  = (float*)(ws + OB_BC);
  _Float16* h0   = (_Float16*)(ws + OB_H0);
  _Float16* h1   = (_Float16*)(ws + OB_H1);
  unsigned* gs   = (unsigned*)(ws + OB_GC);

  // zero h ping-pong + barrier counters every call (graph-replay safe)
  hipMemsetAsync((void*)(ws + OB_H0), 0, OB_END - OB_H0, stream);

  k_combo<<<36, 256, 0, stream>>>(W_h2o, W_h2h, b_h2h, b_h2o, Wcombo, bcombo);
  k_wblk<<<1024, 256, 0, stream>>>(W_hh, W_ih, W_h2o, W_h2h, Whf);
  k_bias<<<16, 256, 0, stream>>>(b_ih, b_hh, W_hh, W_ih, b_h2h, bcombo, b0, bconst);
  k_fillx<<<2048, 256, 0, stream>>>(W_ih, Whf);
  k_len<<<1, 256, 0, stream>>>(lens, dout);

  k_main<<<256, 1024, 0, stream>>>(x, Whf, Wcombo, b0, bconst, bcombo, h0, h1, gs, dout);
}

// Round 9
// 7216.426 us; speedup vs baseline: 2.6610x; 1.7541x over previous
//
#include <hip/hip_runtime.h>
#include <math.h>

#define TB 256      // batch
#define TT 512      // timesteps
#define TIN 128     // input size
#define TH 1024     // hidden
#define TOUT 9      // output coords
#define KD 1152     // TIN + TH

typedef _Float16 half8 __attribute__((ext_vector_type(8)));
typedef float f32x4 __attribute__((ext_vector_type(4)));

// ---- workspace layout (BYTE offsets) ----
#define OB_WHF   0ull
#define SB_WHF   (128ull*2*36*64*8*2)   // 9,437,184 B  f16 B-fragments [wcg][nt][kc][l][j]
#define OB_WCB   (OB_WHF + SB_WHF)      // Wcombo fp32 [9][1024]
#define SB_WCB   (9ull*1024*4)
#define OB_BCB   (OB_WCB + SB_WCB)      // bcombo fp32 [9] (pad 16)
#define SB_BCB   64ull
#define OB_B0    (OB_BCB + SB_BCB)      // bias t==0 [4096] fp32
#define SB_B0    (4096ull*4)
#define OB_BC    (OB_B0 + SB_B0)        // bias t>0  [4096] fp32
#define SB_BC    (4096ull*4)
#define OB_H0    (OB_BC + SB_BC)        // h_cell ping [256][1024] f16
#define SB_H     (256ull*1024*2)
#define OB_H1    (OB_H0 + SB_H)         // h_cell pong
#define OB_GC    (OB_H1 + SB_H)         // barrier counters (two halves, 128B lines)
#define OB_END   (OB_GC + 8192ull)      // ~10.5 MB total

// fragment address for gate col `col` (0..4095), k (0..1151):
//   q=col>>10 (gate), hcol=col&1023, wcg=hcol>>3, jj=hcol&7, c=(q<<3)|jj,
//   nt=c>>4, n=c&15, kc=k>>5, ls=(k>>3)&3, je=k&7, lane=(ls<<4)|n
__device__ __forceinline__ size_t frag_addr(int col, int k) {
  int q = col >> 10, hcol = col & 1023;
  int wcg = hcol >> 3, jj = hcol & 7;
  int c = (q << 3) | jj;
  int nt = c >> 4, n = c & 15;
  int kc = k >> 5, ls = (k >> 3) & 3, je = k & 7;
  return ((((size_t)wcg * 2 + nt) * 36 + kc) * 64 + ((ls << 4) | n)) * 8 + je;
}

// ---- agent-scope (LLC write-through) 16B h store as 2x8B relaxed atomics ----
__device__ __forceinline__ void st_h16_agent(_Float16* p, uint4 v) {
  union { uint4 q; unsigned long long u[2]; } c; c.q = v;
  __hip_atomic_store((unsigned long long*)p,     c.u[0], __ATOMIC_RELAXED, __HIP_MEMORY_SCOPE_AGENT);
  __hip_atomic_store((unsigned long long*)p + 1, c.u[1], __ATOMIC_RELAXED, __HIP_MEMORY_SCOPE_AGENT);
}

// ---------------- prep kernels (unchanged, verified rounds 5-8) ----------------

__global__ __launch_bounds__(256) void k_combo(const float* __restrict__ W_h2o,
                                               const float* __restrict__ W_h2h,
                                               const float* __restrict__ b_h2h,
                                               const float* __restrict__ b_h2o,
                                               float* __restrict__ Wcombo,
                                               float* __restrict__ bcombo) {
  int gid = blockIdx.x * 256 + threadIdx.x;
  if (gid < 9 * 1024) {
    int r = gid >> 10, m = gid & 1023;
    float s = 0.f;
    for (int j = 0; j < 1024; ++j) s += W_h2o[r * 1024 + j] * W_h2h[j * 1024 + m];
    Wcombo[gid] = s;
  }
  if (gid < 9) {
    float s = b_h2o[gid];
    for (int j = 0; j < 1024; ++j) s += W_h2o[gid * 1024 + j] * b_h2h[j];
    bcombo[gid] = s;
  }
}

__global__ __launch_bounds__(256) void k_wblk(const float* __restrict__ W_hh,
                                              const float* __restrict__ W_ih,
                                              const float* __restrict__ W_h2o,
                                              const float* __restrict__ W_h2h,
                                              _Float16* __restrict__ Whf) {
  __shared__ float As2[16][68];
  __shared__ float Bs[16][68];
  __shared__ float Wio_s[64][12];
  __shared__ float Bo[9][16];
  const int tid = threadIdx.x;
  const int bm = (blockIdx.x & 15) * 64;   // m tile
  const int bc = (blockIdx.x >> 4) * 64;   // col tile
  const int tx = tid & 15, ty = tid >> 4;
  const int cl = tid >> 2, kq4 = tid & 3;

  for (int i = tid; i < 64 * 9; i += 256) {
    int row = i / 9, r = i % 9;
    Wio_s[row][r] = W_ih[(size_t)(bc + row) * 137 + 128 + r];
  }

  float acc[4][4];
#pragma unroll
  for (int i = 0; i < 4; ++i)
#pragma unroll
    for (int j = 0; j < 4; ++j) acc[i][j] = 0.f;

  for (int k0 = 0; k0 < 1024; k0 += 16) {
    __syncthreads();
    if (tid < 144) { int r = tid >> 4, kk = tid & 15; Bo[r][kk] = W_h2o[(size_t)r * 1024 + k0 + kk]; }
    { int kk = tid >> 4, q = tid & 15;
      float4 v = *(const float4*)(W_h2h + (size_t)(k0 + kk) * 1024 + bm + q * 4);
      *(float4*)&Bs[kk][q * 4] = v; }
    float4 av = *(const float4*)(W_hh + (size_t)(bc + cl) * 1024 + k0 + kq4 * 4);
    __syncthreads();
    {
      float c0 = 0.f, c1 = 0.f, c2 = 0.f, c3 = 0.f;
#pragma unroll
      for (int r = 0; r < 9; ++r) {
        float wio = Wio_s[cl][r];
        c0 += wio * Bo[r][kq4 * 4 + 0];
        c1 += wio * Bo[r][kq4 * 4 + 1];
        c2 += wio * Bo[r][kq4 * 4 + 2];
        c3 += wio * Bo[r][kq4 * 4 + 3];
      }
      As2[kq4 * 4 + 0][cl] = av.x + c0;
      As2[kq4 * 4 + 1][cl] = av.y + c1;
      As2[kq4 * 4 + 2][cl] = av.z + c2;
      As2[kq4 * 4 + 3][cl] = av.w + c3;
    }
    __syncthreads();
#pragma unroll
    for (int kk = 0; kk < 16; ++kk) {
      float4 a = *(const float4*)&As2[kk][ty * 4];
      float4 bv = *(const float4*)&Bs[kk][tx * 4];
      acc[0][0] += a.x * bv.x; acc[0][1] += a.x * bv.y; acc[0][2] += a.x * bv.z; acc[0][3] += a.x * bv.w;
      acc[1][0] += a.y * bv.x; acc[1][1] += a.y * bv.y; acc[1][2] += a.y * bv.z; acc[1][3] += a.y * bv.w;
      acc[2][0] += a.z * bv.x; acc[2][1] += a.z * bv.y; acc[2][2] += a.z * bv.z; acc[2][3] += a.z * bv.w;
      acc[3][0] += a.w * bv.x; acc[3][1] += a.w * bv.y; acc[3][2] += a.w * bv.z; acc[3][3] += a.w * bv.w;
    }
  }
#pragma unroll
  for (int i = 0; i < 4; ++i)
#pragma unroll
    for (int j = 0; j < 4; ++j) {
      int col = bc + ty * 4 + i;          // gate col
      int m = bm + tx * 4 + j;            // h index -> k = 128+m
      Whf[frag_addr(col, 128 + m)] = (_Float16)acc[i][j];
    }
}

__global__ __launch_bounds__(256) void k_bias(const float* __restrict__ b_ih,
                                              const float* __restrict__ b_hh,
                                              const float* __restrict__ W_hh,
                                              const float* __restrict__ W_ih,
                                              const float* __restrict__ b_h2h,
                                              const float* __restrict__ bcombo,
                                              float* __restrict__ b0,
                                              float* __restrict__ bconst) {
  int col = blockIdx.x * 256 + threadIdx.x;
  float base = b_ih[col] + b_hh[col];
  b0[col] = base;
  float s = 0.f;
  for (int j = 0; j < 1024; ++j) s += W_hh[(size_t)col * 1024 + j] * b_h2h[j];
#pragma unroll
  for (int r = 0; r < 9; ++r) s += W_ih[(size_t)col * 137 + 128 + r] * bcombo[r];
  bconst[col] = base + s;
}

__global__ __launch_bounds__(256) void k_fillx(const float* __restrict__ W_ih,
                                               _Float16* __restrict__ Whf) {
  int gid = blockIdx.x * 256 + threadIdx.x;   // 4096*128
  int col = gid >> 7, k = gid & 127;
  Whf[frag_addr(col, k)] = (_Float16)W_ih[(size_t)col * 137 + k];
}

__global__ void k_len(const int* __restrict__ len, float* __restrict__ dout) {
  int i = threadIdx.x;
  if (i < TB) dout[(size_t)TB * TT * TOUT + i] = (float)len[i];
}

// ---------------- persistent main kernel ----------------
// 256 blocks x 1024 thr, 1/CU. Grid = 2 INDEPENDENT batch-halves (block only
// touches its half's h/x/dout) -> two separate 128-block tree barriers (8x16).
// Block = (half_id, wcg). W fragments LDS-resident all 512 steps. Waves:
// mt=wv&7, kh=wv>>3. A-fragment loads software-pipelined (all 18 issued into
// registers before the MFMA loop). h: write-through agent atomics + cached
// reads + one invalidate-only ACQUIRE per block per step (proven r7/r8).
// out(t-1): waves 1..9 compute all 9 cols for this block's ONE batch (uniform
// work, no stragglers); wave 0 free so tid0 lead path starts immediately.

__device__ __forceinline__ float sigm(float v) { return 1.f / (1.f + __expf(-v)); }
__device__ __forceinline__ float tanh_f(float v) {
  float e2 = __expf(2.f * v);
  return (e2 - 1.f) / (e2 + 1.f);
}

__global__ __launch_bounds__(1024, 1) void k_main(const float* __restrict__ x,
                                                  const _Float16* __restrict__ Whf,
                                                  const float* __restrict__ Wc,
                                                  const float* __restrict__ b0,
                                                  const float* __restrict__ bcf,
                                                  const float* __restrict__ bcombo,
                                                  _Float16* __restrict__ hA,
                                                  _Float16* __restrict__ hB,
                                                  unsigned* __restrict__ gs,
                                                  float* __restrict__ dout) {
  __shared__ _Float16 Wl[2 * 36 * 64 * 8];   // 73,728 B
  __shared__ float gbuf[2][128][36];         // 36,864 B (K-half partials)
  __shared__ _Float16 htmp[128][8];          //  2,048 B
  __shared__ float bias_s[2][32];
  __shared__ float bco_s[12];
  __shared__ int sAbort;

  const int bx = blockIdx.x;
  const int half_id = bx >> 7;       // 0/1: independent batch-half
  const int wcg = bx & 127;          // col-group: h-cols 8*wcg..+7
  const int B0 = half_id * 128;      // batch base
  const int myb = B0 + wcg;          // this block's out-GEMV batch
  const int grp = wcg >> 4;          // barrier group within half (8 groups x 16)
  const int tid = threadIdx.x;
  const int lane = tid & 63;
  const int wv = tid >> 6;
  const int mt = wv & 7, kh = wv >> 3;

  unsigned* hbase = gs + half_id * 1024;     // per-half barrier region
  unsigned* gcnt_grp = hbase + grp * 32;     // arrival counter (own 128B line)
  unsigned* gcnt_root = hbase + 8 * 32;      // root counter (8 leads)
  unsigned* grel = hbase + (9 + grp) * 32;   // group release word
  unsigned* gabort = gs + 1984;              // global abort flag (shared)

  {  // stage W fragments once (reused 512 steps)
    const uint4* src = (const uint4*)(Whf + (size_t)wcg * (2 * 36 * 64 * 8));
    uint4* dst = (uint4*)Wl;
    for (int i = tid; i < 2 * 36 * 64 * 8 / 8; i += 1024) dst[i] = src[i];
  }
  if (tid == 0) sAbort = 0;
  if (tid < 9) bco_s[tid] = bcombo[tid];
  if (tid < 32) {
    int g = (tid >> 3) * 1024 + wcg * 8 + (tid & 7);   // c=(q<<3)|jj -> gate col
    bias_s[0][tid] = b0[g];
    bias_s[1][tid] = bcf[g];
  }
  float cs = 0.f;   // cell state of (batch B0+(tid>>3), h-col 8*wcg+(tid&7))
  __syncthreads();

  const _Float16* ha = hA;   // h_cell(t-1), zeroed by memset
  _Float16* hn = hB;

  const int bA = B0 + mt * 16 + (lane & 15);   // A-fragment batch row
  const int ko = (lane >> 4) * 8;              // A-fragment k offset within 32-chunk
  const _Float16* wl0 = Wl + (size_t)lane * 8;
  const _Float16* wlb = wl0 + (size_t)(kh * 18) * 512;
  unsigned myLead = 0;

  for (int t = 0; t < TT; ++t) {
    // ---- A-fragment loads: ALL issued before the MFMA loop (pipelined) ----
    f32x4 acc0 = {0.f, 0.f, 0.f, 0.f};
    f32x4 acc1 = {0.f, 0.f, 0.f, 0.f};
    const _Float16* hrow = ha + (size_t)bA * TH;
    half8 af[18];
    if (kh == 0) {
      const float* xrow = x + ((size_t)bA * TT + t) * TIN;
      float4 xv[8];
#pragma unroll
      for (int i = 0; i < 4; ++i) {
        xv[2 * i]     = *(const float4*)(xrow + i * 32 + ko);
        xv[2 * i + 1] = *(const float4*)(xrow + i * 32 + ko + 4);
      }
#pragma unroll
      for (int lc = 4; lc < 18; ++lc)
        af[lc] = *(const half8*)(hrow + (lc * 32 - 128 + ko));
#pragma unroll
      for (int i = 0; i < 4; ++i) {
        half8 a;
        a[0] = (_Float16)xv[2 * i].x; a[1] = (_Float16)xv[2 * i].y;
        a[2] = (_Float16)xv[2 * i].z; a[3] = (_Float16)xv[2 * i].w;
        a[4] = (_Float16)xv[2 * i + 1].x; a[5] = (_Float16)xv[2 * i + 1].y;
        a[6] = (_Float16)xv[2 * i + 1].z; a[7] = (_Float16)xv[2 * i + 1].w;
        af[i] = a;
      }
    } else {
#pragma unroll
      for (int lc = 0; lc < 18; ++lc)
        af[lc] = *(const half8*)(hrow + ((18 + lc) * 32 - 128 + ko));
    }
    // ---- MFMA loop: B from LDS, A from registers ----
#pragma unroll
    for (int lc = 0; lc < 18; ++lc) {
      half8 bf0 = *(const half8*)(wlb + (size_t)lc * 512);
      half8 bf1 = *(const half8*)(wlb + (size_t)(36 + lc) * 512);
      acc0 = __builtin_amdgcn_mfma_f32_16x16x32_f16(af[lc], bf0, acc0, 0, 0, 0);
      acc1 = __builtin_amdgcn_mfma_f32_16x16x32_f16(af[lc], bf1, acc1, 0, 0, 0);
    }
    {  // D layout: col = lane&15, row = (lane>>4)*4 + r
      int rb = mt * 16 + (lane >> 4) * 4;
      int cc = lane & 15;
#pragma unroll
      for (int r = 0; r < 4; ++r) {
        gbuf[kh][rb + r][cc] = acc0[r];
        gbuf[kh][rb + r][16 + cc] = acc1[r];
      }
    }
    __syncthreads();

    // ---- LSTM finish: thread owns (fb=tid>>3, fj=tid&7); cs in registers ----
    {
      const int fb = tid >> 3, fj = tid & 7;
      const float* bs = bias_s[(t > 0) ? 1 : 0];
      float vi = gbuf[0][fb][fj]      + gbuf[1][fb][fj]      + bs[fj];
      float vf = gbuf[0][fb][8 + fj]  + gbuf[1][fb][8 + fj]  + bs[8 + fj];
      float vg = gbuf[0][fb][16 + fj] + gbuf[1][fb][16 + fj] + bs[16 + fj];
      float vo = gbuf[0][fb][24 + fj] + gbuf[1][fb][24 + fj] + bs[24 + fj];
      float ig = sigm(vi), fg = sigm(vf), gg = tanh_f(vg), og = sigm(vo);
      float cn = fg * cs + ig * gg;
      cs = cn;
      htmp[fb][fj] = (_Float16)(og * tanh_f(cn));
    }
    __syncthreads();

    // ---- h store: write-through to LLC (agent atomics) ----
    if (tid < 128) {
      uint4 hv = *(const uint4*)&htmp[tid][0];
      st_h16_agent(hn + (size_t)(B0 + tid) * TH + 8 * wcg, hv);
    }
    __threadfence_block();   // drain own vmcnt: stores visible at LLC
    __syncthreads();         // whole block drained

    // ---- barrier arrival (relaxed: data already at LLC) ----
    if (tid == 0) {
      unsigned old = __hip_atomic_fetch_add(gcnt_grp, 1u, __ATOMIC_RELAXED, __HIP_MEMORY_SCOPE_AGENT);
      myLead = (old == (unsigned)(t + 1) * 16u - 1u);
    }

    // ---- out(t-1): waves 1..9, all 9 cols for this block's one batch ----
    if ((unsigned)(wv - 1) < 9u && t > 0) {
      const int r = wv - 1;
      const _Float16* hro = ha + (size_t)myb * TH + lane * 16;
      const float* wcp = Wc + r * 1024 + lane * 16;
      half8 h0v = *(const half8*)(hro);
      half8 h1v = *(const half8*)(hro + 8);
      float s = 0.f;
#pragma unroll
      for (int i = 0; i < 8; ++i)
        s += (float)h0v[i] * wcp[i] + (float)h1v[i] * wcp[8 + i];
#pragma unroll
      for (int off = 32; off > 0; off >>= 1) s += __shfl_down(s, off, 64);
      if (lane == 0) dout[((size_t)myb * TT + (t - 1)) * TOUT + r] = s + bco_s[r];
    }

    // ---- barrier spin (per-half tree; bounded; abort) + invalidate acquire ----
    if (tid == 0) {
      bool ab = false;
      unsigned guard = 0;
      if (myLead) {
        __hip_atomic_fetch_add(gcnt_root, 1u, __ATOMIC_RELAXED, __HIP_MEMORY_SCOPE_AGENT);
        while (__hip_atomic_load(gcnt_root, __ATOMIC_RELAXED, __HIP_MEMORY_SCOPE_AGENT) < (unsigned)(t + 1) * 8u) {
          __builtin_amdgcn_s_sleep(1);
          if (((++guard) & 255u) == 0u &&
              __hip_atomic_load(gabort, __ATOMIC_RELAXED, __HIP_MEMORY_SCOPE_AGENT) != 0u) { ab = true; break; }
          if (guard > 200000u) {
            __hip_atomic_store(gabort, 1u, __ATOMIC_RELAXED, __HIP_MEMORY_SCOPE_AGENT);
            ab = true; break;
          }
        }
        if (!ab) __hip_atomic_store(grel, (unsigned)(t + 1), __ATOMIC_RELAXED, __HIP_MEMORY_SCOPE_AGENT);
      } else {
        while (__hip_atomic_load(grel, __ATOMIC_RELAXED, __HIP_MEMORY_SCOPE_AGENT) < (unsigned)(t + 1)) {
          __builtin_amdgcn_s_sleep(1);
          if (((++guard) & 255u) == 0u &&
              __hip_atomic_load(gabort, __ATOMIC_RELAXED, __HIP_MEMORY_SCOPE_AGENT) != 0u) { ab = true; break; }
          if (guard > 200000u) {
            __hip_atomic_store(gabort, 1u, __ATOMIC_RELAXED, __HIP_MEMORY_SCOPE_AGENT);
            ab = true; break;
          }
        }
      }
      if (ab) {
        sAbort = 1;
      } else {
        // ACQUIRE load: emits buffer_inv (invalidate stale L1/L2), no wbl2.
        (void)__hip_atomic_load(grel, __ATOMIC_ACQUIRE, __HIP_MEMORY_SCOPE_AGENT);
      }
    }
    __syncthreads();
    if (sAbort) return;   // wrong answer beats a wedged GPU

    const _Float16* tp = ha; ha = hn; hn = (_Float16*)tp;
  }

  // ---- epilogue: out(TT-1) for this block's batch from final h ----
  if ((unsigned)(wv - 1) < 9u) {
    const int r = wv - 1;
    const _Float16* hro = ha + (size_t)myb * TH + lane * 16;
    const float* wcp = Wc + r * 1024 + lane * 16;
    half8 h0v = *(const half8*)(hro);
    half8 h1v = *(const half8*)(hro + 8);
    float s = 0.f;
#pragma unroll
    for (int i = 0; i < 8; ++i)
      s += (float)h0v[i] * wcp[i] + (float)h1v[i] * wcp[8 + i];
#pragma unroll
    for (int off = 32; off > 0; off >>= 1) s += __shfl_down(s, off, 64);
    if (lane == 0) dout[((size_t)myb * TT + (TT - 1)) * TOUT + r] = s + bco_s[r];
  }
}

// ---------------- launch ----------------

extern "C" void kernel_launch(void* const* d_in, const int* in_sizes, int n_in,
                              void* d_out, int out_size, void* d_ws, size_t ws_size,
                              hipStream_t stream) {
  if (ws_size < OB_END) return;   // clean fail, no OOB

  const float* x     = (const float*)d_in[0];
  const float* W_ih  = (const float*)d_in[1];
  const float* b_ih  = (const float*)d_in[2];
  const float* W_hh  = (const float*)d_in[3];
  const float* b_hh  = (const float*)d_in[4];
  const float* W_h2h = (const float*)d_in[5];
  const float* b_h2h = (const float*)d_in[6];
  const float* W_h2o = (const float*)d_in[7];
  const float* b_h2o = (const float*)d_in[8];
  const int*   lens  = (const int*)d_in[9];

  char* ws = (char*)d_ws;
  float* dout    = (float*)d_out;
  _Float16* Whf  = (_Float16*)(ws + OB_WHF);
  float* Wcombo  = (float*)(ws + OB_WCB);
  float* bcombo  = (float*)(ws + OB_BCB);
  float* b0      = (float*)(ws + OB_B0);
  float* bconst  = (float*)(ws + OB_BC);
  _Float16* h0   = (_Float16*)(ws + OB_H0);
  _Float16* h1   = (_Float16*)(ws + OB_H1);
  unsigned* gs   = (unsigned*)(ws + OB_GC);

  // zero h ping-pong + barrier counters every call (graph-replay safe)
  hipMemsetAsync((void*)(ws + OB_H0), 0, OB_END - OB_H0, stream);

  k_combo<<<36, 256, 0, stream>>>(W_h2o, W_h2h, b_h2h, b_h2o, Wcombo, bcombo);
  k_wblk<<<1024, 256, 0, stream>>>(W_hh, W_ih, W_h2o, W_h2h, Whf);
  k_bias<<<16, 256, 0, stream>>>(b_ih, b_hh, W_hh, W_ih, b_h2h, bcombo, b0, bconst);
  k_fillx<<<2048, 256, 0, stream>>>(W_ih, Whf);
  k_len<<<1, 256, 0, stream>>>(lens, dout);

  k_main<<<256, 1024, 0, stream>>>(x, Whf, Wcombo, b0, bconst, bcombo, h0, h1, gs, dout);
}